// Round 1
// baseline (154.649 us; speedup 1.0000x reference)
//
#include <hip/hip_runtime.h>
#include <math.h>

#define NN   8192
#define CIN  256
#define COUT 128
#define MAXE 1024

// ---------------------------------------------------------------------------
// Kernel 1: h = X@W + b ; f1 = h@v0 ; f2 = h@v1  (all fp32)
// Block: 256 threads. Tile: 16 rows x 128 cols.
// Thread (ct = tid&63, rg = tid>>6): cols c = 2*ct, 2*ct+1; rows rg*4 .. rg*4+3.
// W chunk (32 k x 2 cols) held in registers; X tile staged in LDS, read as
// broadcast float4 (all 64 lanes of a wave share rg -> same address).
// ---------------------------------------------------------------------------
__global__ __launch_bounds__(256) void k1_gemm(
    const float* __restrict__ X, const float* __restrict__ W,
    const float* __restrict__ b, const float* __restrict__ v0,
    const float* __restrict__ v1,
    float* __restrict__ h, float* __restrict__ f1, float* __restrict__ f2)
{
    __shared__ float Xs[16][32];
    const int tid = threadIdx.x;
    const int ct  = tid & 63;
    const int rg  = tid >> 6;
    const int c   = ct * 2;
    const int row0 = blockIdx.x * 16;

    float acc[4][2] = {{0.f,0.f},{0.f,0.f},{0.f,0.f},{0.f,0.f}};

    for (int kc = 0; kc < CIN; kc += 32) {
        // stage X tile [16 rows][32 k]
        if (tid < 128) {
            const int r = tid >> 3, q = tid & 7;
            const float4 xv = *(const float4*)(X + (size_t)(row0 + r) * CIN + kc + q * 4);
            *(float4*)&Xs[r][q * 4] = xv;
        }
        // W chunk into registers (coalesced float2, L2-hot)
        float2 wv[32];
        #pragma unroll
        for (int kk = 0; kk < 32; ++kk)
            wv[kk] = *(const float2*)(W + (size_t)(kc + kk) * COUT + c);
        __syncthreads();

        #pragma unroll
        for (int rr = 0; rr < 4; ++rr) {
            const int lr = rg * 4 + rr;
            #pragma unroll
            for (int k4 = 0; k4 < 8; ++k4) {
                const float4 xv = *(const float4*)&Xs[lr][k4 * 4];
                acc[rr][0] += xv.x * wv[k4*4+0].x; acc[rr][1] += xv.x * wv[k4*4+0].y;
                acc[rr][0] += xv.y * wv[k4*4+1].x; acc[rr][1] += xv.y * wv[k4*4+1].y;
                acc[rr][0] += xv.z * wv[k4*4+2].x; acc[rr][1] += xv.z * wv[k4*4+2].y;
                acc[rr][0] += xv.w * wv[k4*4+3].x; acc[rr][1] += xv.w * wv[k4*4+3].y;
            }
        }
        __syncthreads();
    }

    const float b0 = b[c], b1 = b[c+1];
    const float v00 = v0[c], v01 = v0[c+1];
    const float v10 = v1[c], v11 = v1[c+1];

    #pragma unroll
    for (int rr = 0; rr < 4; ++rr) {
        const int row = row0 + rg * 4 + rr;
        const float h0 = acc[rr][0] + b0;
        const float h1 = acc[rr][1] + b1;
        *(float2*)(h + (size_t)row * COUT + c) = make_float2(h0, h1);
        float p0 = h0 * v00 + h1 * v01;
        float p1 = h0 * v10 + h1 * v11;
        #pragma unroll
        for (int off = 32; off; off >>= 1) {
            p0 += __shfl_down(p0, off, 64);
            p1 += __shfl_down(p1, off, 64);
        }
        if (ct == 0) { f1[row] = p0; f2[row] = p1; }
    }
}

// ---------------------------------------------------------------------------
// Kernel 2: per-row sparse softmax + attn@h. One block (256 threads) per row.
// Phase A: float4 scan of adj row, compact (j, sigmoid(f1i+f2j)-0.5) into LDS.
// Phase B: block-reduce max; Phase C: exp + block-reduce sum;
// Phase D: out[i,c] = sum_j e_j * h[j,c] / denom  (2 column-groups of 128).
// ---------------------------------------------------------------------------
__global__ __launch_bounds__(256) void k2_attn(
    const float* __restrict__ adj, const float* __restrict__ h,
    const float* __restrict__ f1, const float* __restrict__ f2,
    float* __restrict__ out)
{
    __shared__ unsigned cnt;
    __shared__ int   jl[MAXE];
    __shared__ float vl[MAXE];
    __shared__ float red[8];
    __shared__ float sacc[256];

    const int tid = threadIdx.x;
    const int i   = blockIdx.x;
    if (tid == 0) cnt = 0;
    __syncthreads();

    const float f1i = f1[i];
    const float4* rowp = (const float4*)(adj + (size_t)i * NN);

    #pragma unroll
    for (int it = 0; it < 8; ++it) {
        const int idx = tid + it * 256;
        const float4 v = rowp[idx];
        if (v.x != 0.f || v.y != 0.f || v.z != 0.f || v.w != 0.f) {
            const int j0 = idx * 4;
            #define PUSH_EDGE(COMP, OFS)                                        \
                if (COMP != 0.f) {                                              \
                    const int j = j0 + OFS;                                     \
                    const float x = f1i + f2[j];                                \
                    const float s = 1.f / (1.f + __expf(-x)) - 0.5f;            \
                    const unsigned p = atomicAdd(&cnt, 1u);                     \
                    if (p < MAXE) { jl[p] = j; vl[p] = s; }                     \
                }
            PUSH_EDGE(v.x, 0)
            PUSH_EDGE(v.y, 1)
            PUSH_EDGE(v.z, 2)
            PUSH_EDGE(v.w, 3)
            #undef PUSH_EDGE
        }
    }
    __syncthreads();

    const int n = (int)min(cnt, (unsigned)MAXE);
    if (n == 0) {
        if (tid < COUT) out[(size_t)i * COUT + tid] = 0.f;
        return;
    }

    // ---- block max ----
    float m = -1e30f;
    for (int p = tid; p < n; p += 256) m = fmaxf(m, vl[p]);
    #pragma unroll
    for (int off = 32; off; off >>= 1) m = fmaxf(m, __shfl_down(m, off, 64));
    if ((tid & 63) == 0) red[tid >> 6] = m;
    __syncthreads();
    m = fmaxf(fmaxf(red[0], red[1]), fmaxf(red[2], red[3]));

    // ---- exp + block sum ----
    float s = 0.f;
    for (int p = tid; p < n; p += 256) {
        const float e = __expf(vl[p] - m);
        vl[p] = e;
        s += e;
    }
    #pragma unroll
    for (int off = 32; off; off >>= 1) s += __shfl_down(s, off, 64);
    if ((tid & 63) == 0) red[4 + (tid >> 6)] = s;
    __syncthreads();
    const float inv = 1.f / (red[4] + red[5] + red[6] + red[7]);

    // ---- weighted sum of h rows ----
    const int c = tid & 127;
    const int g = tid >> 7;
    float acc = 0.f;
    for (int p = g; p < n; p += 2)
        acc += vl[p] * h[(size_t)jl[p] * COUT + c];
    sacc[tid] = acc;
    __syncthreads();
    if (tid < COUT)
        out[(size_t)i * COUT + c] = (sacc[tid] + sacc[tid + 128]) * inv;
}

extern "C" void kernel_launch(void* const* d_in, const int* in_sizes, int n_in,
                              void* d_out, int out_size, void* d_ws, size_t ws_size,
                              hipStream_t stream) {
    const float* X   = (const float*)d_in[0];
    const float* adj = (const float*)d_in[1];
    const float* W   = (const float*)d_in[2];
    const float* b   = (const float*)d_in[3];
    const float* v0  = (const float*)d_in[4];
    const float* v1  = (const float*)d_in[5];
    float* out = (float*)d_out;

    float* h  = (float*)d_ws;                 // 8192*128 f32 = 4 MB
    float* f1 = h + (size_t)NN * COUT;        // 32 KB
    float* f2 = f1 + NN;                      // 32 KB

    k1_gemm<<<NN / 16, 256, 0, stream>>>(X, W, b, v0, v1, h, f1, f2);
    k2_attn<<<NN, 256, 0, stream>>>(adj, h, f1, f2, out);
}

// Round 2
// 94.608 us; speedup vs baseline: 1.6346x; 1.6346x over previous
//
#include <hip/hip_runtime.h>
#include <math.h>

#define NN   8192
#define CIN  256
#define COUT 128
#define MAXE 1024

// ---------------------------------------------------------------------------
// Kernel 1: h = X@W + b ; f1 = h@v0 ; f2 = h@v1  (all fp32)
// ---------------------------------------------------------------------------
__global__ __launch_bounds__(256) void k1_gemm(
    const float* __restrict__ X, const float* __restrict__ W,
    const float* __restrict__ b, const float* __restrict__ v0,
    const float* __restrict__ v1,
    float* __restrict__ h, float* __restrict__ f1, float* __restrict__ f2)
{
    __shared__ float Xs[16][32];
    const int tid = threadIdx.x;
    const int ct  = tid & 63;
    const int rg  = tid >> 6;
    const int c   = ct * 2;
    const int row0 = blockIdx.x * 16;

    float acc[4][2] = {{0.f,0.f},{0.f,0.f},{0.f,0.f},{0.f,0.f}};

    for (int kc = 0; kc < CIN; kc += 32) {
        if (tid < 128) {
            const int r = tid >> 3, q = tid & 7;
            const float4 xv = *(const float4*)(X + (size_t)(row0 + r) * CIN + kc + q * 4);
            *(float4*)&Xs[r][q * 4] = xv;
        }
        float2 wv[32];
        #pragma unroll
        for (int kk = 0; kk < 32; ++kk)
            wv[kk] = *(const float2*)(W + (size_t)(kc + kk) * COUT + c);
        __syncthreads();

        #pragma unroll
        for (int rr = 0; rr < 4; ++rr) {
            const int lr = rg * 4 + rr;
            #pragma unroll
            for (int k4 = 0; k4 < 8; ++k4) {
                const float4 xv = *(const float4*)&Xs[lr][k4 * 4];
                acc[rr][0] += xv.x * wv[k4*4+0].x; acc[rr][1] += xv.x * wv[k4*4+0].y;
                acc[rr][0] += xv.y * wv[k4*4+1].x; acc[rr][1] += xv.y * wv[k4*4+1].y;
                acc[rr][0] += xv.z * wv[k4*4+2].x; acc[rr][1] += xv.z * wv[k4*4+2].y;
                acc[rr][0] += xv.w * wv[k4*4+3].x; acc[rr][1] += xv.w * wv[k4*4+3].y;
            }
        }
        __syncthreads();
    }

    const float b0 = b[c], b1 = b[c+1];
    const float v00 = v0[c], v01 = v0[c+1];
    const float v10 = v1[c], v11 = v1[c+1];

    #pragma unroll
    for (int rr = 0; rr < 4; ++rr) {
        const int row = row0 + rg * 4 + rr;
        const float h0 = acc[rr][0] + b0;
        const float h1 = acc[rr][1] + b1;
        *(float2*)(h + (size_t)row * COUT + c) = make_float2(h0, h1);
        float p0 = h0 * v00 + h1 * v01;
        float p1 = h0 * v10 + h1 * v11;
        #pragma unroll
        for (int off = 32; off; off >>= 1) {
            p0 += __shfl_down(p0, off, 64);
            p1 += __shfl_down(p1, off, 64);
        }
        if (ct == 0) { f1[row] = p0; f2[row] = p1; }
    }
}

// ---------------------------------------------------------------------------
// Kernel 2: one block (256 threads) per row.
// A: hoisted register loads of the adj row (8 float4/thread in flight at
//    block start), compact ONLY the column index j into LDS (adj vals are 1.0).
// B: parallel pass over compacted list: vl[p] = sigmoid(f1i+f2[j]) - 0.5.
// C: block max, exp, block sum.
// D: 4 wave-groups, float2 columns, 4-deep unroll -> 16 h-row loads in flight.
// ---------------------------------------------------------------------------
__global__ __launch_bounds__(256) void k2_attn(
    const float* __restrict__ adj, const float* __restrict__ h,
    const float* __restrict__ f1, const float* __restrict__ f2,
    float* __restrict__ out)
{
    __shared__ unsigned cnt;
    __shared__ int    jl[MAXE];
    __shared__ float  vl[MAXE];
    __shared__ float  red[8];
    __shared__ float2 sacc[4][64];

    const int tid = threadIdx.x;
    const int i   = blockIdx.x;

    // ---- A: issue all adjacency loads first (pure MLP, no LDS deps) ----
    const float4* rowp = (const float4*)(adj + (size_t)i * NN);
    float4 v[8];
    #pragma unroll
    for (int it = 0; it < 8; ++it) v[it] = rowp[tid + it * 256];

    if (tid == 0) cnt = 0;
    __syncthreads();

    #pragma unroll
    for (int it = 0; it < 8; ++it) {
        if (v[it].x != 0.f || v[it].y != 0.f || v[it].z != 0.f || v[it].w != 0.f) {
            const int j0 = (tid + it * 256) * 4;
            if (v[it].x != 0.f) { const unsigned p = atomicAdd(&cnt, 1u); if (p < MAXE) jl[p] = j0;     }
            if (v[it].y != 0.f) { const unsigned p = atomicAdd(&cnt, 1u); if (p < MAXE) jl[p] = j0 + 1; }
            if (v[it].z != 0.f) { const unsigned p = atomicAdd(&cnt, 1u); if (p < MAXE) jl[p] = j0 + 2; }
            if (v[it].w != 0.f) { const unsigned p = atomicAdd(&cnt, 1u); if (p < MAXE) jl[p] = j0 + 3; }
        }
    }
    __syncthreads();

    const int n = (int)min(cnt, (unsigned)MAXE);
    if (n == 0) {
        if (tid < COUT) out[(size_t)i * COUT + tid] = 0.f;
        return;
    }

    // ---- B: parallel sigmoid over compacted edges ----
    const float f1i = f1[i];
    for (int p = tid; p < n; p += 256) {
        const float x = f1i + f2[jl[p]];
        vl[p] = 1.f / (1.f + __expf(-x)) - 0.5f;
    }
    __syncthreads();

    // ---- C: block max, then exp + block sum ----
    float m = -1e30f;
    for (int p = tid; p < n; p += 256) m = fmaxf(m, vl[p]);
    #pragma unroll
    for (int off = 32; off; off >>= 1) m = fmaxf(m, __shfl_down(m, off, 64));
    if ((tid & 63) == 0) red[tid >> 6] = m;
    __syncthreads();
    m = fmaxf(fmaxf(red[0], red[1]), fmaxf(red[2], red[3]));

    float s = 0.f;
    for (int p = tid; p < n; p += 256) {
        const float e = __expf(vl[p] - m);
        vl[p] = e;
        s += e;
    }
    #pragma unroll
    for (int off = 32; off; off >>= 1) s += __shfl_down(s, off, 64);
    if ((tid & 63) == 0) red[4 + (tid >> 6)] = s;
    __syncthreads();
    const float inv = 1.f / (red[4] + red[5] + red[6] + red[7]);

    // ---- D: weighted sum of h rows; 4 wave-groups, float2, 4-deep unroll ----
    const int g  = tid >> 6;   // wave id -> no intra-wave divergence
    const int ct = tid & 63;
    const int c  = ct * 2;
    float ax = 0.f, ay = 0.f;
    int p = g;
    for (; p + 12 < n; p += 16) {
        const int   j0 = jl[p],     j1 = jl[p + 4], j2 = jl[p + 8], j3 = jl[p + 12];
        const float w0 = vl[p],     w1 = vl[p + 4], w2 = vl[p + 8], w3 = vl[p + 12];
        const float2 a0 = *(const float2*)(h + (size_t)j0 * COUT + c);
        const float2 a1 = *(const float2*)(h + (size_t)j1 * COUT + c);
        const float2 a2 = *(const float2*)(h + (size_t)j2 * COUT + c);
        const float2 a3 = *(const float2*)(h + (size_t)j3 * COUT + c);
        ax += w0 * a0.x + w1 * a1.x + w2 * a2.x + w3 * a3.x;
        ay += w0 * a0.y + w1 * a1.y + w2 * a2.y + w3 * a3.y;
    }
    for (; p < n; p += 4) {
        const int   j = jl[p];
        const float w = vl[p];
        const float2 a = *(const float2*)(h + (size_t)j * COUT + c);
        ax += w * a.x;
        ay += w * a.y;
    }
    sacc[g][ct] = make_float2(ax, ay);
    __syncthreads();
    if (tid < 64) {
        const float2 r0 = sacc[0][tid], r1 = sacc[1][tid];
        const float2 r2 = sacc[2][tid], r3 = sacc[3][tid];
        float2 r;
        r.x = (r0.x + r1.x + r2.x + r3.x) * inv;
        r.y = (r0.y + r1.y + r2.y + r3.y) * inv;
        *(float2*)(out + (size_t)i * COUT + tid * 2) = r;
    }
}

extern "C" void kernel_launch(void* const* d_in, const int* in_sizes, int n_in,
                              void* d_out, int out_size, void* d_ws, size_t ws_size,
                              hipStream_t stream) {
    const float* X   = (const float*)d_in[0];
    const float* adj = (const float*)d_in[1];
    const float* W   = (const float*)d_in[2];
    const float* b   = (const float*)d_in[3];
    const float* v0  = (const float*)d_in[4];
    const float* v1  = (const float*)d_in[5];
    float* out = (float*)d_out;

    float* h  = (float*)d_ws;                 // 8192*128 f32 = 4 MB
    float* f1 = h + (size_t)NN * COUT;        // 32 KB
    float* f2 = f1 + NN;                      // 32 KB

    k1_gemm<<<NN / 16, 256, 0, stream>>>(X, W, b, v0, v1, h, f1, f2);
    k2_attn<<<NN, 256, 0, stream>>>(adj, h, f1, f2, out);
}

// Round 4
// 88.411 us; speedup vs baseline: 1.7492x; 1.0701x over previous
//
#include <hip/hip_runtime.h>
#include <math.h>

#define NN    8192
#define CIN   256
#define COUT  128
#define NK1   512      // k1 GEMM blocks (16 rows each)
#define MAXEG 256      // max edges stored per row (mean ~82, sigma ~9 -> 19 sigma)

typedef unsigned uvec4 __attribute__((ext_vector_type(4)));

// ---------------------------------------------------------------------------
// Kernel A: blockIdx < NK1  -> k1 GEMM  (h = X@W + b, f1 = h@v0, f2 = h@v1)
//           blockIdx >= NK1 -> adjacency row scan -> packed u16 edge list.
// Edge list for row i is written into d_out row i (512 B), consumed and
// overwritten by kernel B (same block reads then writes -> no hazard).
// ---------------------------------------------------------------------------
__global__ __launch_bounds__(256) void kA(
    const float* __restrict__ X, const float* __restrict__ adj,
    const float* __restrict__ W, const float* __restrict__ b,
    const float* __restrict__ v0, const float* __restrict__ v1,
    float* __restrict__ h, float* __restrict__ f1, float* __restrict__ f2,
    unsigned* __restrict__ cnt, unsigned* __restrict__ outw)
{
    __shared__ float Xs[16][32];
    __shared__ unsigned scnt;
    __shared__ unsigned short sjl[MAXEG];

    const int tid = threadIdx.x;

    if (blockIdx.x < NK1) {
        // ---------------- GEMM part ----------------
        const int ct  = tid & 63;
        const int rg  = tid >> 6;
        const int c   = ct * 2;
        const int row0 = blockIdx.x * 16;

        float acc[4][2] = {{0.f,0.f},{0.f,0.f},{0.f,0.f},{0.f,0.f}};

        for (int kc = 0; kc < CIN; kc += 32) {
            if (tid < 128) {
                const int r = tid >> 3, q = tid & 7;
                const float4 xv = *(const float4*)(X + (size_t)(row0 + r) * CIN + kc + q * 4);
                *(float4*)&Xs[r][q * 4] = xv;
            }
            float2 wv[32];
            #pragma unroll
            for (int kk = 0; kk < 32; ++kk)
                wv[kk] = *(const float2*)(W + (size_t)(kc + kk) * COUT + c);
            __syncthreads();

            #pragma unroll
            for (int rr = 0; rr < 4; ++rr) {
                const int lr = rg * 4 + rr;
                #pragma unroll
                for (int k4 = 0; k4 < 8; ++k4) {
                    const float4 xv = *(const float4*)&Xs[lr][k4 * 4];
                    acc[rr][0] += xv.x * wv[k4*4+0].x; acc[rr][1] += xv.x * wv[k4*4+0].y;
                    acc[rr][0] += xv.y * wv[k4*4+1].x; acc[rr][1] += xv.y * wv[k4*4+1].y;
                    acc[rr][0] += xv.z * wv[k4*4+2].x; acc[rr][1] += xv.z * wv[k4*4+2].y;
                    acc[rr][0] += xv.w * wv[k4*4+3].x; acc[rr][1] += xv.w * wv[k4*4+3].y;
                }
            }
            __syncthreads();
        }

        const float b0 = b[c], b1 = b[c+1];
        const float v00 = v0[c], v01 = v0[c+1];
        const float v10 = v1[c], v11 = v1[c+1];

        #pragma unroll
        for (int rr = 0; rr < 4; ++rr) {
            const int row = row0 + rg * 4 + rr;
            const float h0 = acc[rr][0] + b0;
            const float h1 = acc[rr][1] + b1;
            *(float2*)(h + (size_t)row * COUT + c) = make_float2(h0, h1);
            float p0 = h0 * v00 + h1 * v01;
            float p1 = h0 * v10 + h1 * v11;
            #pragma unroll
            for (int off = 32; off; off >>= 1) {
                p0 += __shfl_down(p0, off, 64);
                p1 += __shfl_down(p1, off, 64);
            }
            if (ct == 0) { f1[row] = p0; f2[row] = p1; }
        }
    } else {
        // ---------------- scan part: pure stream + compact ----------------
        const int i = blockIdx.x - NK1;
        const uvec4* rowp = (const uvec4*)(adj + (size_t)i * NN);
        uvec4 v[8];
        #pragma unroll
        for (int it = 0; it < 8; ++it)
            v[it] = __builtin_nontemporal_load(rowp + tid + it * 256);

        if (tid == 0) scnt = 0;
        __syncthreads();

        #pragma unroll
        for (int it = 0; it < 8; ++it) {
            if (v[it].x | v[it].y | v[it].z | v[it].w) {
                const int j0 = (tid + it * 256) * 4;
                if (v[it].x) { const unsigned p = atomicAdd(&scnt, 1u); if (p < MAXEG) sjl[p] = (unsigned short)(j0    ); }
                if (v[it].y) { const unsigned p = atomicAdd(&scnt, 1u); if (p < MAXEG) sjl[p] = (unsigned short)(j0 + 1); }
                if (v[it].z) { const unsigned p = atomicAdd(&scnt, 1u); if (p < MAXEG) sjl[p] = (unsigned short)(j0 + 2); }
                if (v[it].w) { const unsigned p = atomicAdd(&scnt, 1u); if (p < MAXEG) sjl[p] = (unsigned short)(j0 + 3); }
            }
        }
        __syncthreads();

        if (tid < 128) {
            const unsigned w = (unsigned)sjl[2 * tid] | ((unsigned)sjl[2 * tid + 1] << 16);
            outw[(size_t)i * 128 + tid] = w;    // packed edge list lives in out row i
        }
        if (tid == 0) cnt[i] = min(scnt, (unsigned)MAXEG);
    }
}

// ---------------------------------------------------------------------------
// Kernel B: per-row softmax + gather. One block (256 threads) per row.
// Reads the packed edge list from out row i, overwrites out row i at the end.
// ---------------------------------------------------------------------------
__global__ __launch_bounds__(256) void kB(
    const float* __restrict__ h, const float* __restrict__ f1,
    const float* __restrict__ f2, const unsigned* __restrict__ cnt,
    float* __restrict__ out)
{
    __shared__ unsigned short jl[MAXEG];
    __shared__ float  vl[MAXEG];
    __shared__ float  red[8];
    __shared__ float2 sacc[4][64];

    const int tid = threadIdx.x;
    const int i   = blockIdx.x;
    const int n   = (int)cnt[i];

    if (n == 0) {
        if (tid < COUT) out[(size_t)i * COUT + tid] = 0.f;
        return;
    }

    if (tid < 128) {
        const unsigned w = ((const unsigned*)out)[(size_t)i * 128 + tid];
        jl[2 * tid]     = (unsigned short)(w & 0xffffu);
        jl[2 * tid + 1] = (unsigned short)(w >> 16);
    }
    __syncthreads();

    // ---- sigmoid (one edge per thread; n <= 256) ----
    float m = -1e30f;
    if (tid < n) {
        const float x = f1[i] + f2[jl[tid]];
        const float s = 1.f / (1.f + __expf(-x)) - 0.5f;
        vl[tid] = s;
        m = s;
    }
    #pragma unroll
    for (int off = 32; off; off >>= 1) m = fmaxf(m, __shfl_down(m, off, 64));
    if ((tid & 63) == 0) red[tid >> 6] = m;
    __syncthreads();
    m = fmaxf(fmaxf(red[0], red[1]), fmaxf(red[2], red[3]));

    float s = 0.f;
    if (tid < n) {
        s = __expf(vl[tid] - m);
        vl[tid] = s;
    }
    #pragma unroll
    for (int off = 32; off; off >>= 1) s += __shfl_down(s, off, 64);
    if ((tid & 63) == 0) red[4 + (tid >> 6)] = s;
    __syncthreads();
    const float inv = 1.f / (red[4] + red[5] + red[6] + red[7]);

    // ---- weighted sum of h rows: 4 wave-groups, float2, 4-deep unroll ----
    const int g  = tid >> 6;
    const int ct = tid & 63;
    const int c  = ct * 2;
    float ax = 0.f, ay = 0.f;
    int p = g;
    for (; p + 12 < n; p += 16) {
        const int   j0 = jl[p],     j1 = jl[p + 4], j2 = jl[p + 8], j3 = jl[p + 12];
        const float w0 = vl[p],     w1 = vl[p + 4], w2 = vl[p + 8], w3 = vl[p + 12];
        const float2 a0 = *(const float2*)(h + (size_t)j0 * COUT + c);
        const float2 a1 = *(const float2*)(h + (size_t)j1 * COUT + c);
        const float2 a2 = *(const float2*)(h + (size_t)j2 * COUT + c);
        const float2 a3 = *(const float2*)(h + (size_t)j3 * COUT + c);
        ax += w0 * a0.x + w1 * a1.x + w2 * a2.x + w3 * a3.x;
        ay += w0 * a0.y + w1 * a1.y + w2 * a2.y + w3 * a3.y;
    }
    for (; p < n; p += 4) {
        const int   j = jl[p];
        const float w = vl[p];
        const float2 a = *(const float2*)(h + (size_t)j * COUT + c);
        ax += w * a.x;
        ay += w * a.y;
    }
    sacc[g][ct] = make_float2(ax, ay);
    __syncthreads();
    if (tid < 64) {
        const float2 r0 = sacc[0][tid], r1 = sacc[1][tid];
        const float2 r2 = sacc[2][tid], r3 = sacc[3][tid];
        float2 r;
        r.x = (r0.x + r1.x + r2.x + r3.x) * inv;
        r.y = (r0.y + r1.y + r2.y + r3.y) * inv;
        *(float2*)(out + (size_t)i * COUT + tid * 2) = r;
    }
}

extern "C" void kernel_launch(void* const* d_in, const int* in_sizes, int n_in,
                              void* d_out, int out_size, void* d_ws, size_t ws_size,
                              hipStream_t stream) {
    const float* X   = (const float*)d_in[0];
    const float* adj = (const float*)d_in[1];
    const float* W   = (const float*)d_in[2];
    const float* b   = (const float*)d_in[3];
    const float* v0  = (const float*)d_in[4];
    const float* v1  = (const float*)d_in[5];
    float* out = (float*)d_out;

    float*    h   = (float*)d_ws;                  // 8192*128 f32 = 4 MB
    float*    f1  = h + (size_t)NN * COUT;         // 32 KB
    float*    f2  = f1 + NN;                       // 32 KB
    unsigned* cnt = (unsigned*)(f2 + NN);          // 32 KB

    kA<<<NK1 + NN, 256, 0, stream>>>(X, adj, W, b, v0, v1, h, f1, f2, cnt, (unsigned*)out);
    kB<<<NN, 256, 0, stream>>>(h, f1, f2, cnt, out);
}